// Round 2
// baseline (209.001 us; speedup 1.0000x reference)
//
#include <hip/hip_runtime.h>
#include <math.h>

#define B_TOTAL 16384
#define D 64
#define L_U 50
#define N_F 32
#define L_I 50

// Per-wave LDS layout (floats). part: 64 lanes * 8 floats (bijective XOR
// swizzle) + slack. su*/sw*: 64-float score scatter buffers per attention.
#define PART_OFF 0
#define SUA_OFF  520
#define SWA_OFF  584
#define SUB_OFF  648
#define SUC_OFF  712
#define SWC_OFF  776
#define WAVE_FL  848   // 3392 B per wave, 13568 B per 256-thread block

// ---------------------------------------------------------------------------
// Setup: u[0..63]=W1@W3, u[64..]=W2@W3, u[128..]=W4@W6, u[192..]=W5@W6,
//        u[256..]=W7@W9, u[320..]=W8@W9
// ---------------------------------------------------------------------------
__global__ void graphrec_setup(const float* __restrict__ W1, const float* __restrict__ W2,
                               const float* __restrict__ W3, const float* __restrict__ W4,
                               const float* __restrict__ W5, const float* __restrict__ W6,
                               const float* __restrict__ W7, const float* __restrict__ W8,
                               const float* __restrict__ W9, float* __restrict__ u) {
    int t = threadIdx.x;           // 0..383
    int w = t >> 6;                // which of 6 vectors
    int d = t & 63;
    const float* Wm;
    const float* Wv;
    switch (w) {
        case 0: Wm = W1; Wv = W3; break;
        case 1: Wm = W2; Wv = W3; break;
        case 2: Wm = W4; Wv = W6; break;
        case 3: Wm = W5; Wv = W6; break;
        case 4: Wm = W7; Wv = W9; break;
        default: Wm = W8; Wv = W9; break;
    }
    float s = 0.f;
    #pragma unroll
    for (int j = 0; j < D; ++j) s = fmaf(Wm[d * D + j], Wv[j], s);
    u[w * D + d] = s;
}

// ---------------------------------------------------------------------------
// Wave-wide reductions via DPP (VALU only). Result uniform via readlane 63.
// ---------------------------------------------------------------------------
__device__ __forceinline__ float wred_sum(float x) {
    float t;
    #define STEP_ADD(ctrl, rmask)                                                        \
        t = __int_as_float(__builtin_amdgcn_update_dpp(0, __float_as_int(x),             \
                                                       ctrl, rmask, 0xf, false));        \
        x = x + t;
    STEP_ADD(0x111, 0xf)
    STEP_ADD(0x112, 0xf)
    STEP_ADD(0x114, 0xf)
    STEP_ADD(0x118, 0xf)
    STEP_ADD(0x142, 0xa)
    STEP_ADD(0x143, 0xc)
    #undef STEP_ADD
    return __int_as_float(__builtin_amdgcn_readlane(__float_as_int(x), 63));
}
__device__ __forceinline__ float wred_max(float x) {
    const int NEG_INF = 0xFF800000;
    float t;
    #define STEP_MAX(ctrl, rmask)                                                        \
        t = __int_as_float(__builtin_amdgcn_update_dpp(NEG_INF, __float_as_int(x),       \
                                                       ctrl, rmask, 0xf, false));        \
        x = fmaxf(x, t);
    STEP_MAX(0x111, 0xf)
    STEP_MAX(0x112, 0xf)
    STEP_MAX(0x114, 0xf)
    STEP_MAX(0x118, 0xf)
    STEP_MAX(0x142, 0xa)
    STEP_MAX(0x143, 0xc)
    #undef STEP_MAX
    return __int_as_float(__builtin_amdgcn_readlane(__float_as_int(x), 63));
}

// 8-lane segmented inclusive sum via DPP row_shr. Valid at lanes with
// (lane&7)==7: lane 8k+7 holds sum of lanes 8k..8k+7 (shift-in zeros only
// affect lanes with c<7; row_shr never crosses the 16-lane DPP row).
__device__ __forceinline__ float segred8(float x) {
    float t;
    t = __int_as_float(__builtin_amdgcn_update_dpp(0, __float_as_int(x), 0x111, 0xf, 0xf, false));
    x = x + t;
    t = __int_as_float(__builtin_amdgcn_update_dpp(0, __float_as_int(x), 0x112, 0xf, 0xf, false));
    x = x + t;
    t = __int_as_float(__builtin_amdgcn_update_dpp(0, __float_as_int(x), 0x114, 0xf, 0xf, false));
    x = x + t;
    return x;
}

// ---------------------------------------------------------------------------
// Register staging: lane (sub=lane>>3, c=lane&7) holds floats [8c..8c+7] of
// row 8g+sub for each group g. Rows beyond L-1 clamp to L-1 (w=0 later).
// ---------------------------------------------------------------------------
template <int L, int NG>
__device__ __forceinline__ void stage8(const float* __restrict__ table,
                                       int idxreg, int sub, int co, float4* buf) {
    #pragma unroll
    for (int g = 0; g < NG; ++g) {
        int r = 8 * g + sub;
        if (r > L - 1) r = L - 1;
        int ridx = __builtin_amdgcn_ds_bpermute(r << 2, idxreg);
        const float* p = table + (unsigned)((ridx << 6) + co);   // 32-bit voffset
        buf[2 * g]     = *(const float4*)(p);
        buf[2 * g + 1] = *(const float4*)(p + 4);
    }
}

// ---------------------------------------------------------------------------
// Fully register-resident attention. LDS used only for two tiny transposes:
// score scatter (rows -> lane=row) and the 8-way sub-class fold of the
// weighted sum. Fold swizzle: logical float j of lane stored at
// lane*8 + (j ^ (lane&4)) -- bijective (XOR half-swap), banks uniform:
// lanes 0..7 cover all 32 banks once per b128 store.
// ---------------------------------------------------------------------------
template <int L, int NG, bool HAS_R>
__device__ __forceinline__ float attn8(float cq, const float* __restrict__ u2,
                                       const float* __restrict__ wa, float r,
                                       int lane, int sub, int cc,
                                       const float4* buf, float* __restrict__ su,
                                       float* __restrict__ sw,
                                       float* __restrict__ part) {
    const float4 uu0 = ((const float4*)u2)[2 * cc];
    const float4 uu1 = ((const float4*)u2)[2 * cc + 1];
    float4 ww0 = {0.f, 0.f, 0.f, 0.f}, ww1 = {0.f, 0.f, 0.f, 0.f};
    if (HAS_R) {
        ww0 = ((const float4*)wa)[2 * cc];
        ww1 = ((const float4*)wa)[2 * cc + 1];
    }

    // ---- dot products in registers + DPP segmented reduce + LDS scatter
    #pragma unroll
    for (int g = 0; g < NG; ++g) {
        const float4 n0 = buf[2 * g];
        const float4 n1 = buf[2 * g + 1];
        float du = fmaf(n0.x, uu0.x, fmaf(n0.y, uu0.y, fmaf(n0.z, uu0.z,
                   fmaf(n0.w, uu0.w, fmaf(n1.x, uu1.x, fmaf(n1.y, uu1.y,
                   fmaf(n1.z, uu1.z, n1.w * uu1.w)))))));
        du = segred8(du);
        if (HAS_R) {
            float dw = fmaf(n0.x, ww0.x, fmaf(n0.y, ww0.y, fmaf(n0.z, ww0.z,
                       fmaf(n0.w, ww0.w, fmaf(n1.x, ww1.x, fmaf(n1.y, ww1.y,
                       fmaf(n1.z, ww1.z, n1.w * ww1.w)))))));
            dw = segred8(dw);
            if (cc == 7) { su[8 * g + sub] = du; sw[8 * g + sub] = dw; }
        } else {
            if (cc == 7) su[8 * g + sub] = du;
        }
    }

    // ---- softmax in lane=row layout (lanes >= L masked; garbage-safe:
    // select replaces the whole value, NaN from uninit LDS is discarded)
    float sc = cq + su[lane];
    if (HAS_R) sc = fmaf(r, sw[lane], sc);
    sc = (lane < L) ? sc : -1e30f;
    const float m = wred_max(sc);
    const float e = __expf(sc - m);
    const float s = wred_sum(e);
    const float w = e * (1.0f / s);

    // ---- weighted sum: w back to (sub,c) layout via bpermute, FMA in regs
    float4 a0 = {0.f, 0.f, 0.f, 0.f}, a1 = {0.f, 0.f, 0.f, 0.f};
    #pragma unroll
    for (int g = 0; g < NG; ++g) {
        const float wv = __int_as_float(
            __builtin_amdgcn_ds_bpermute((8 * g + sub) << 2, __float_as_int(w)));
        const float4 n0 = buf[2 * g];
        const float4 n1 = buf[2 * g + 1];
        a0.x = fmaf(wv, n0.x, a0.x); a0.y = fmaf(wv, n0.y, a0.y);
        a0.z = fmaf(wv, n0.z, a0.z); a0.w = fmaf(wv, n0.w, a0.w);
        a1.x = fmaf(wv, n1.x, a1.x); a1.y = fmaf(wv, n1.y, a1.y);
        a1.z = fmaf(wv, n1.z, a1.z); a1.w = fmaf(wv, n1.w, a1.w);
    }

    // ---- fold the 8 sub-class partials through LDS.
    // Bijective XOR swizzle: a0 (j=0..3) at pw+s4, a1 (j=4..7) at pw+(4^s4).
    const int s4 = lane & 4;
    const int pw = lane << 3;
    *(float4*)(part + pw + s4)       = a0;
    *(float4*)(part + pw + (4 ^ s4)) = a1;
    // Reader of (s2, d=lane): writer lane' = s2*8 + (lane>>3), whose &4 bit
    // is lane bit 5 -> rb = (lane&56) + ((lane&7) ^ ((lane>>3)&4)).
    const int rb = (lane & 56) + ((lane & 7) ^ ((lane >> 3) & 4));
    float acc = 0.f;
    #pragma unroll
    for (int s2 = 0; s2 < 8; ++s2) acc += part[rb + 64 * s2];
    return acc;
}

__global__ __launch_bounds__(256, 4) void graphrec_fwd(
        const int* __restrict__ user_ids, const int* __restrict__ item_ids,
        const int* __restrict__ uh_items, const float* __restrict__ uh_rat,
        const int* __restrict__ ufriends,
        const int* __restrict__ ih_users, const float* __restrict__ ih_rat,
        const float* __restrict__ eu, const float* __restrict__ ei,
        const float* __restrict__ W3, const float* __restrict__ W6,
        const float* __restrict__ W9,
        const float* __restrict__ fc1w, const float* __restrict__ fc1b,
        const float* __restrict__ fc2w, const float* __restrict__ fc2b,
        const float* __restrict__ u, float* __restrict__ out) {
    // LDS: 13568 B/block (was 52224). Occupancy now VGPR-bound: <=128 VGPR
    // -> 4 waves/SIMD = 16 waves/CU. No barriers anywhere (per-wave buffers,
    // DS pipe is in-order within a wave).
    __shared__ __align__(16) float smem[4 * WAVE_FL];
    const int lane = threadIdx.x & 63;
    const int wv = threadIdx.x >> 6;
    const int b = blockIdx.x * 4 + wv;
    float* ws = smem + wv * WAVE_FL;
    const int sub = lane >> 3;       // row-within-group
    const int cc  = lane & 7;        // 8-float chunk id
    const int co  = cc << 3;         // float offset of chunk

    // Per-lane neighbor metadata (lane l holds slot l).
    int idxA = 0, idxB = 0, idxC = 0;
    float rA = 0.f, rC = 0.f;
    if (lane < L_U) {
        idxA = uh_items[b * L_U + lane];
        rA   = uh_rat[b * L_U + lane];
        idxC = ih_users[b * L_I + lane];
        rC   = ih_rat[b * L_I + lane];
    }
    if (lane < N_F) idxB = ufriends[b * N_F + lane];

    // Prefetch A and B gathers into registers (88 VGPRs in flight).
    float4 bufA[14];
    float4 bufB[8];
    stage8<L_U, 7>(ei, idxA, sub, co, bufA);
    stage8<N_F, 4>(eu, idxB, sub, co, bufB);

    const int uid = user_ids[b];
    const int iid = item_ids[b];
    const float qu = eu[(size_t)uid * D + lane];
    const float qi = ei[(size_t)iid * D + lane];

    // cq = q . (Wq@Wa) for each attention (DPP reduce -> uniform); runs
    // while the gathers are in flight.
    const float cqa = wred_sum(qu * u[lane]);
    const float cqb = wred_sum(qu * u[128 + lane]);
    const float cqc = wred_sum(qi * u[256 + lane]);

    // ---- A (user <- rated items)
    const float accA = attn8<L_U, 7, true >(cqa, u + 64, W3, rA, lane, sub, cc,
                                            bufA, ws + SUA_OFF, ws + SWA_OFF,
                                            ws + PART_OFF);
    // bufA's registers are dead now: issue C's gather so it flies under B.
    float4 bufC[14];
    stage8<L_I, 7>(eu, idxC, sub, co, bufC);

    // ---- B (user <- friends)
    const float accB = attn8<N_F, 4, false>(cqb, u + 192, W6, 0.f, lane, sub, cc,
                                            bufB, ws + SUB_OFF, ws + SUB_OFF,
                                            ws + PART_OFF);
    // ---- C (item <- interacting users)
    const float accC = attn8<L_I, 7, true >(cqc, u + 320, W9, rC, lane, sub, cc,
                                            bufC, ws + SUC_OFF, ws + SWC_OFF,
                                            ws + PART_OFF);

    const float uf  = qu + accA + accB;   // user_emb_final[lane]
    const float itf = qi + accC;          // item_emb_final[lane]

    // MLP: 4 accumulators break the 128-deep fma chain; fc1w reads are
    // coalesced 256 B rows, L1-hot across waves.
    float h0 = fc1b[lane], h1 = 0.f, h2 = 0.f, h3 = 0.f;
    #pragma unroll
    for (int k = 0; k < D; k += 4) {
        h0 = fmaf(__int_as_float(__builtin_amdgcn_readlane(__float_as_int(uf), k + 0)),
                  fc1w[(k + 0) * D + lane], h0);
        h1 = fmaf(__int_as_float(__builtin_amdgcn_readlane(__float_as_int(uf), k + 1)),
                  fc1w[(k + 1) * D + lane], h1);
        h2 = fmaf(__int_as_float(__builtin_amdgcn_readlane(__float_as_int(uf), k + 2)),
                  fc1w[(k + 2) * D + lane], h2);
        h3 = fmaf(__int_as_float(__builtin_amdgcn_readlane(__float_as_int(uf), k + 3)),
                  fc1w[(k + 3) * D + lane], h3);
    }
    #pragma unroll
    for (int k = 0; k < D; k += 4) {
        h0 = fmaf(__int_as_float(__builtin_amdgcn_readlane(__float_as_int(itf), k + 0)),
                  fc1w[(D + k + 0) * D + lane], h0);
        h1 = fmaf(__int_as_float(__builtin_amdgcn_readlane(__float_as_int(itf), k + 1)),
                  fc1w[(D + k + 1) * D + lane], h1);
        h2 = fmaf(__int_as_float(__builtin_amdgcn_readlane(__float_as_int(itf), k + 2)),
                  fc1w[(D + k + 2) * D + lane], h2);
        h3 = fmaf(__int_as_float(__builtin_amdgcn_readlane(__float_as_int(itf), k + 3)),
                  fc1w[(D + k + 3) * D + lane], h3);
    }
    const float h = fmaxf((h0 + h1) + (h2 + h3), 0.f);
    const float o = wred_sum(h * fc2w[lane]);
    if (lane == 0) out[b] = o + fc2b[0];
}

extern "C" void kernel_launch(void* const* d_in, const int* in_sizes, int n_in,
                              void* d_out, int out_size, void* d_ws, size_t ws_size,
                              hipStream_t stream) {
    const int*   user_ids = (const int*)d_in[0];
    const int*   item_ids = (const int*)d_in[1];
    const int*   uh_items = (const int*)d_in[2];
    const float* uh_rat   = (const float*)d_in[3];
    const int*   ufriends = (const int*)d_in[4];
    const int*   ih_users = (const int*)d_in[5];
    const float* ih_rat   = (const float*)d_in[6];
    const float* eu       = (const float*)d_in[7];
    const float* ei       = (const float*)d_in[8];
    const float* W1 = (const float*)d_in[9];
    const float* W2 = (const float*)d_in[10];
    const float* W3 = (const float*)d_in[11];
    const float* W4 = (const float*)d_in[12];
    const float* W5 = (const float*)d_in[13];
    const float* W6 = (const float*)d_in[14];
    const float* W7 = (const float*)d_in[15];
    const float* W8 = (const float*)d_in[16];
    const float* W9 = (const float*)d_in[17];
    const float* fc1w = (const float*)d_in[18];
    const float* fc1b = (const float*)d_in[19];
    const float* fc2w = (const float*)d_in[20];
    const float* fc2b = (const float*)d_in[21];
    float* out = (float*)d_out;
    float* u   = (float*)d_ws;   // 6 * 64 floats = 1536 B

    graphrec_setup<<<1, 384, 0, stream>>>(W1, W2, W3, W4, W5, W6, W7, W8, W9, u);
    graphrec_fwd<<<B_TOTAL / 4, 256, 0, stream>>>(
        user_ids, item_ids, uh_items, uh_rat, ufriends, ih_users, ih_rat,
        eu, ei, W3, W6, W9, fc1w, fc1b, fc2w, fc2b, u, out);
}